// Round 8
// baseline (133.283 us; speedup 1.0000x reference)
//
#include <hip/hip_runtime.h>

typedef __bf16 bf16_t;
typedef __bf16 bf16x8 __attribute__((ext_vector_type(8)));
typedef __bf16 bf16x4 __attribute__((ext_vector_type(4)));
typedef float  f32x4  __attribute__((ext_vector_type(4)));
typedef _Float16 f16_t;
typedef _Float16 f16x8 __attribute__((ext_vector_type(8)));
typedef _Float16 f16x4 __attribute__((ext_vector_type(4)));

#define TSEQ 4096
#define SEGS 8

// lgkm-only barrier (proj): in-flight global prefetches survive it.
__device__ __forceinline__ void barrier_lds() {
    __builtin_amdgcn_sched_barrier(0);
    asm volatile("s_waitcnt lgkmcnt(0)" ::: "memory");
    __builtin_amdgcn_s_barrier();
    __builtin_amdgcn_sched_barrier(0);
}

// ---------------------------------------------------------------------------
// wsplit: W[1024][64] (q,k,v fp32) -> wT[192][1024] bf16 (transposed).
// Wq pre-scaled by 0.125*log2(e) so attention scores land in exp2 domain.
// ---------------------------------------------------------------------------
__global__ __launch_bounds__(256) void wsplit_k(
    const float* __restrict__ Wq, const float* __restrict__ Wk,
    const float* __restrict__ Wv, bf16_t* __restrict__ wT)
{
    __shared__ bf16_t th[64][72];
    const int mat = blockIdx.x >> 4;
    const int kb  = (blockIdx.x & 15) * 64;
    const float* W = (mat == 0) ? Wq : ((mat == 1) ? Wk : Wv);
    const float scale = (mat == 0) ? 0.18033688011112042f : 1.0f;
    const int t  = threadIdx.x;
    const int kl = t >> 2;
    const int dc = (t & 3) * 16;
    #pragma unroll
    for (int i = 0; i < 4; ++i) {
        float4 v = *reinterpret_cast<const float4*>(W + (long)(kb + kl) * 64 + dc + 4 * i);
        th[dc + 4*i + 0][kl] = (bf16_t)(v.x * scale);
        th[dc + 4*i + 1][kl] = (bf16_t)(v.y * scale);
        th[dc + 4*i + 2][kl] = (bf16_t)(v.z * scale);
        th[dc + 4*i + 3][kl] = (bf16_t)(v.w * scale);
    }
    __syncthreads();
    const int d  = t >> 2;
    const int kc = (t & 3) * 16;
    bf16x8 a0 = *reinterpret_cast<const bf16x8*>(&th[d][kc]);
    bf16x8 a1 = *reinterpret_cast<const bf16x8*>(&th[d][kc + 8]);
    long o = (long)(mat * 64 + d) * 1024 + kb + kc;
    *reinterpret_cast<bf16x8*>(wT + o)     = a0;
    *reinterpret_cast<bf16x8*>(wT + o + 8) = a1;
}

// ---------------------------------------------------------------------------
// proj: [8192][192] = X @ W^T.  512 blocks = 128 row-groups x 4 N-blocks;
// 4 waves M-split.  X direct-to-frags (2-step ping-pong), W dbuf in LDS.
// In-loop barriers are lgkm-only so X/W prefetches stay in flight.
// ---------------------------------------------------------------------------
__global__ __launch_bounds__(256, 2) void proj_mfma(
    const float* __restrict__ X, const bf16_t* __restrict__ wT,
    bf16_t* __restrict__ qh, bf16_t* __restrict__ kh, bf16_t* __restrict__ vt)
{
    __shared__ __align__(16) unsigned char smem[13824];
    bf16_t (*wl)[48][72] = reinterpret_cast<bf16_t(*)[48][72]>(smem);   // [2][48][72]
    float  (*vtl)[68]    = reinterpret_cast<float(*)[68]>(smem);        // [48][68] (union)

    const int tid = threadIdx.x, lane = tid & 63;
    const int mw  = tid >> 6;
    const int q4 = lane & 15, g = lane >> 4;
    const int bx = blockIdx.x;
    const int rg = bx & 127, nb = bx >> 7;
    const long R0 = (long)rg * 64;

    const float* xrow = X + (R0 + 16 * mw + q4) * 1024 + 8 * g;

    const int wrow = tid >> 2, c16 = (tid & 3) * 16;
    const bf16_t* wsrc = wT + (long)(48 * nb + wrow) * 1024 + c16;
    const bool wact = (tid < 192);

    bf16x8 wr0, wr1;
    float4 xE[4], xO[4];
    f32x4 acc[3] = {};

    auto loadW = [&](int t) {
        if (wact) {
            wr0 = *reinterpret_cast<const bf16x8*>(wsrc + t * 64);
            wr1 = *reinterpret_cast<const bf16x8*>(wsrc + t * 64 + 8);
        }
    };
    auto writeW = [&](int buf) {
        if (wact) {
            *reinterpret_cast<bf16x8*>(&wl[buf][wrow][c16])     = wr0;
            *reinterpret_cast<bf16x8*>(&wl[buf][wrow][c16 + 8]) = wr1;
        }
    };
    auto loadX = [&](int t, float4 (&xc)[4]) {
        xc[0] = *reinterpret_cast<const float4*>(xrow + t * 64);
        xc[1] = *reinterpret_cast<const float4*>(xrow + t * 64 + 4);
        xc[2] = *reinterpret_cast<const float4*>(xrow + t * 64 + 32);
        xc[3] = *reinterpret_cast<const float4*>(xrow + t * 64 + 36);
    };

    loadW(0); writeW(0);
    loadW(1);
    loadX(0, xE); loadX(1, xO);
    asm volatile("" ::: "memory");
    barrier_lds();

    auto stepf = [&](int t, float4 (&xc)[4]) {
        if (t + 1 < 16) {
            writeW((t + 1) & 1);
            loadW(t + 2 < 16 ? t + 2 : 15);
        }
        bf16x8 a0 = {(bf16_t)xc[0].x, (bf16_t)xc[0].y, (bf16_t)xc[0].z, (bf16_t)xc[0].w,
                     (bf16_t)xc[1].x, (bf16_t)xc[1].y, (bf16_t)xc[1].z, (bf16_t)xc[1].w};
        bf16x8 a1 = {(bf16_t)xc[2].x, (bf16_t)xc[2].y, (bf16_t)xc[2].z, (bf16_t)xc[2].w,
                     (bf16_t)xc[3].x, (bf16_t)xc[3].y, (bf16_t)xc[3].z, (bf16_t)xc[3].w};
        if (t + 2 < 16) loadX(t + 2, xc);
        asm volatile("" ::: "memory");
        __builtin_amdgcn_s_setprio(1);
        #pragma unroll
        for (int j = 0; j < 3; ++j) {
            bf16x8 b0 = *reinterpret_cast<const bf16x8*>(&wl[t & 1][16 * j + q4][8 * g]);
            bf16x8 b1 = *reinterpret_cast<const bf16x8*>(&wl[t & 1][16 * j + q4][8 * g + 32]);
            acc[j] = __builtin_amdgcn_mfma_f32_16x16x32_bf16(a0, b0, acc[j], 0, 0, 0);
            acc[j] = __builtin_amdgcn_mfma_f32_16x16x32_bf16(a1, b1, acc[j], 0, 0, 0);
        }
        __builtin_amdgcn_s_setprio(0);
        barrier_lds();
    };
    #pragma unroll
    for (int tt = 0; tt < 16; tt += 2) { stepf(tt, xE); stepf(tt + 1, xO); }

    const int vbase = (nb == 2) ? 0 : 16;
    #pragma unroll
    for (int j = 0; j < 3; ++j) {
        const int nt = 3 * nb + j;
        #pragma unroll
        for (int r = 0; r < 4; ++r) {
            const long row = R0 + 16 * mw + 4 * g + r;
            const float vv = acc[j][r];
            if (nt < 4)      qh[row * 64 + nt * 16 + q4] = (bf16_t)vv;
            else if (nt < 8) kh[row * 64 + (nt - 4) * 16 + q4] = (bf16_t)vv;
            else             vtl[(nt - 8) * 16 + q4 - vbase][16 * mw + 4 * g + r] = vv;
        }
    }
    if (nb >= 2) {
        barrier_lds();
        const int nd = (nb == 2) ? 16 : 48;
        const int dl = tid >> 2, cc = (tid & 3) * 16;
        if (dl < nd) {
            bf16x8 o0, o1;
            #pragma unroll
            for (int i = 0; i < 8; ++i) {
                o0[i] = (bf16_t)vtl[dl][cc + i];
                o1[i] = (bf16_t)vtl[dl][cc + 8 + i];
            }
            bf16_t* dst = vt + (long)(vbase + dl) * 8192 + R0 + cc;
            *reinterpret_cast<bf16x8*>(dst)     = o0;
            *reinterpret_cast<bf16x8*>(dst + 8) = o1;
        }
    }
}

// ---------------------------------------------------------------------------
// attn: flash, 1-wave blocks (16 queries), self-paced, NO barriers.
// ALL K/V fragments in NAMED registers (no arrays/lambdas -> no scratch).
// V issued at loop top (consumed at PV ~250cyc later); K refilled right
// after its last MFMA read (WAR-pinned).  Seg-major block order: the ~16
// co-resident blocks/CU walk the same K/V chunks -> L1/L2 locality.
// ---------------------------------------------------------------------------
__global__ __launch_bounds__(64, 4) void attn_mfma(
    const bf16_t* __restrict__ qh, const bf16_t* __restrict__ kh,
    const bf16_t* __restrict__ vt,
    f16_t* __restrict__ pO, float* __restrict__ pm, float* __restrict__ pl)
{
    __shared__ __align__(16) unsigned char smem[2304];
    bf16_t (*P)[16][8] = reinterpret_cast<bf16_t(*)[16][8]>(smem);  // [8][16][8]
    f16_t  (*ot)[72]   = reinterpret_cast<f16_t(*)[72]>(smem);      // [16][72] overlay

    const int lane = threadIdx.x;
    const int q4 = lane & 15, g = lane >> 4;
    const int bx = blockIdx.x;
    const int b = bx >> 11;
    const int inner = bx & 2047;
    const int seg = inner >> 8;             // seg-major
    const int qi  = 255 - (inner & 255);    // heavy tiles first within seg
    const int C = (qi >> 2) + 1;            // causal 64-key chunk count
    if (seg >= C) return;
    const long base = (long)b * TSEQ;
    const int r0 = qi << 4;
    const int rq = r0 + q4;

    const bf16_t* qr = qh + (base + r0 + q4) * 64 + 8 * g;
    const bf16x8 qf0 = *reinterpret_cast<const bf16x8*>(qr);
    const bf16x8 qf1 = *reinterpret_cast<const bf16x8*>(qr + 32);

    const bf16_t* kbase = kh + (base + q4) * 64 + 8 * g;   // + kb*64 per chunk
    const bf16_t* vbase = vt + (long)q4 * 8192 + base + 8 * g;  // + kb per chunk

    bf16x8 k00, k01, k10, k11, k20, k21, k30, k31;
    bf16x8 v00, v01, v10, v11, v20, v21, v30, v31;

#define LOADK(kb_) do { const bf16_t* kr_ = kbase + (long)(kb_) * 64;          \
    k00 = *reinterpret_cast<const bf16x8*>(kr_);                               \
    k01 = *reinterpret_cast<const bf16x8*>(kr_ + 32);                          \
    k10 = *reinterpret_cast<const bf16x8*>(kr_ + 1024);                        \
    k11 = *reinterpret_cast<const bf16x8*>(kr_ + 1056);                        \
    k20 = *reinterpret_cast<const bf16x8*>(kr_ + 2048);                        \
    k21 = *reinterpret_cast<const bf16x8*>(kr_ + 2080);                        \
    k30 = *reinterpret_cast<const bf16x8*>(kr_ + 3072);                        \
    k31 = *reinterpret_cast<const bf16x8*>(kr_ + 3104); } while (0)

#define LOADV(kb_) do { const bf16_t* vr_ = vbase + (kb_);                     \
    v00 = *reinterpret_cast<const bf16x8*>(vr_);                               \
    v01 = *reinterpret_cast<const bf16x8*>(vr_ + 32);                          \
    v10 = *reinterpret_cast<const bf16x8*>(vr_ + 131072);                      \
    v11 = *reinterpret_cast<const bf16x8*>(vr_ + 131104);                      \
    v20 = *reinterpret_cast<const bf16x8*>(vr_ + 262144);                      \
    v21 = *reinterpret_cast<const bf16x8*>(vr_ + 262176);                      \
    v30 = *reinterpret_cast<const bf16x8*>(vr_ + 393216);                      \
    v31 = *reinterpret_cast<const bf16x8*>(vr_ + 393248); } while (0)

    float m = -1e30f, l = 0.f;
    f32x4 oacc0 = {}, oacc1 = {}, oacc2 = {}, oacc3 = {};

    LOADK(seg << 6);

    for (int c = seg; c < C; c += SEGS) {
        const int kb = c << 6;
        LOADV(kb);                           // consumed at PV below
        __builtin_amdgcn_sched_barrier(0);   // don't sink V loads

        // ---- QK^T (swapped): S^T[key][query]; reads k-regs
        f32x4 s0 = {}, s1 = {}, s2 = {}, s3 = {};
        s0 = __builtin_amdgcn_mfma_f32_16x16x32_bf16(k00, qf0, s0, 0, 0, 0);
        s0 = __builtin_amdgcn_mfma_f32_16x16x32_bf16(k01, qf1, s0, 0, 0, 0);
        s1 = __builtin_amdgcn_mfma_f32_16x16x32_bf16(k10, qf0, s1, 0, 0, 0);
        s1 = __builtin_amdgcn_mfma_f32_16x16x32_bf16(k11, qf1, s1, 0, 0, 0);
        s2 = __builtin_amdgcn_mfma_f32_16x16x32_bf16(k20, qf0, s2, 0, 0, 0);
        s2 = __builtin_amdgcn_mfma_f32_16x16x32_bf16(k21, qf1, s2, 0, 0, 0);
        s3 = __builtin_amdgcn_mfma_f32_16x16x32_bf16(k30, qf0, s3, 0, 0, 0);
        s3 = __builtin_amdgcn_mfma_f32_16x16x32_bf16(k31, qf1, s3, 0, 0, 0);

        // refill k-regs for next chunk (WAR: issues right after last read)
        if (c + SEGS < C) {
            LOADK((c + SEGS) << 6);
            __builtin_amdgcn_sched_barrier(0);
        }

        // ---- causal mask: diagonal chunk only (uniform branch)
        if (c == C - 1) {
            const int kk = kb + 4 * g;
            #pragma unroll
            for (int r = 0; r < 4; ++r) {
                if (kk +  0 + r > rq) s0[r] = -1e30f;
                if (kk + 16 + r > rq) s1[r] = -1e30f;
                if (kk + 32 + r > rq) s2[r] = -1e30f;
                if (kk + 48 + r > rq) s3[r] = -1e30f;
            }
        }

        // ---- per-query max
        float mx = s0[0];
        #pragma unroll
        for (int r = 0; r < 4; ++r) {
            mx = fmaxf(mx, s0[r]); mx = fmaxf(mx, s1[r]);
            mx = fmaxf(mx, s2[r]); mx = fmaxf(mx, s3[r]);
        }
        mx = fmaxf(mx, __shfl_xor(mx, 16));
        mx = fmaxf(mx, __shfl_xor(mx, 32));

        // ---- exp2 in place; exact defer-rescale when max didn't grow
        float lsum = 0.f;
        if (__all(mx <= m)) {
            #pragma unroll
            for (int r = 0; r < 4; ++r) {
                s0[r] = __builtin_exp2f(s0[r] - m); lsum += s0[r];
                s1[r] = __builtin_exp2f(s1[r] - m); lsum += s1[r];
                s2[r] = __builtin_exp2f(s2[r] - m); lsum += s2[r];
                s3[r] = __builtin_exp2f(s3[r] - m); lsum += s3[r];
            }
        } else {
            const float mnew = fmaxf(m, mx);
            const float alpha = __builtin_exp2f(m - mnew);
            m = mnew;
            #pragma unroll
            for (int r = 0; r < 4; ++r) {
                s0[r] = __builtin_exp2f(s0[r] - mnew); lsum += s0[r];
                s1[r] = __builtin_exp2f(s1[r] - mnew); lsum += s1[r];
                s2[r] = __builtin_exp2f(s2[r] - mnew); lsum += s2[r];
                s3[r] = __builtin_exp2f(s3[r] - mnew); lsum += s3[r];
            }
            oacc0 *= alpha; oacc1 *= alpha; oacc2 *= alpha; oacc3 *= alpha;
            l *= alpha;
        }
        lsum += __shfl_xor(lsum, 16);
        lsum += __shfl_xor(lsum, 32);
        l += lsum;

        // ---- pack P -> per-wave LDS tile (same wave; lgkm only, no barrier)
        {
            const int ki = (g & 1) << 2, cb = g >> 1;
            bf16x4 h0 = {(bf16_t)s0[0], (bf16_t)s0[1], (bf16_t)s0[2], (bf16_t)s0[3]};
            bf16x4 h1 = {(bf16_t)s1[0], (bf16_t)s1[1], (bf16_t)s1[2], (bf16_t)s1[3]};
            bf16x4 h2 = {(bf16_t)s2[0], (bf16_t)s2[1], (bf16_t)s2[2], (bf16_t)s2[3]};
            bf16x4 h3 = {(bf16_t)s3[0], (bf16_t)s3[1], (bf16_t)s3[2], (bf16_t)s3[3]};
            *reinterpret_cast<bf16x4*>(&P[0 + cb][q4][ki]) = h0;
            *reinterpret_cast<bf16x4*>(&P[2 + cb][q4][ki]) = h1;
            *reinterpret_cast<bf16x4*>(&P[4 + cb][q4][ki]) = h2;
            *reinterpret_cast<bf16x4*>(&P[6 + cb][q4][ki]) = h3;
        }
        bf16x8 ph0 = *reinterpret_cast<const bf16x8*>(&P[g][q4][0]);
        bf16x8 ph1 = *reinterpret_cast<const bf16x8*>(&P[4 + g][q4][0]);

        // ---- PV: O^T += V^T x P^T (v-regs issued at loop top)
        oacc0 = __builtin_amdgcn_mfma_f32_16x16x32_bf16(v00, ph0, oacc0, 0, 0, 0);
        oacc0 = __builtin_amdgcn_mfma_f32_16x16x32_bf16(v01, ph1, oacc0, 0, 0, 0);
        oacc1 = __builtin_amdgcn_mfma_f32_16x16x32_bf16(v10, ph0, oacc1, 0, 0, 0);
        oacc1 = __builtin_amdgcn_mfma_f32_16x16x32_bf16(v11, ph1, oacc1, 0, 0, 0);
        oacc2 = __builtin_amdgcn_mfma_f32_16x16x32_bf16(v20, ph0, oacc2, 0, 0, 0);
        oacc2 = __builtin_amdgcn_mfma_f32_16x16x32_bf16(v21, ph1, oacc2, 0, 0, 0);
        oacc3 = __builtin_amdgcn_mfma_f32_16x16x32_bf16(v30, ph0, oacc3, 0, 0, 0);
        oacc3 = __builtin_amdgcn_mfma_f32_16x16x32_bf16(v31, ph1, oacc3, 0, 0, 0);
    }
#undef LOADK
#undef LOADV

    // ---- epilogue: normalize, transpose via LDS (overlays P), store f16
    const float invl = 1.0f / l;
    #pragma unroll
    for (int r = 0; r < 4; ++r) {
        ot[q4][ 0 + 4 * g + r] = (f16_t)(oacc0[r] * invl);
        ot[q4][16 + 4 * g + r] = (f16_t)(oacc1[r] * invl);
        ot[q4][32 + 4 * g + r] = (f16_t)(oacc2[r] * invl);
        ot[q4][48 + 4 * g + r] = (f16_t)(oacc3[r] * invl);
    }

    const long pb = ((long)b * 256 + qi) * SEGS + seg;
    {
        const int q  = lane >> 2;
        const int dc = (lane & 3) << 4;
        f16x8 o0 = *reinterpret_cast<const f16x8*>(&ot[q][dc]);
        f16x8 o1 = *reinterpret_cast<const f16x8*>(&ot[q][dc + 8]);
        f16_t* dst = pO + (pb * 16 + q) * 64 + dc;
        *reinterpret_cast<f16x8*>(dst)     = o0;
        *reinterpret_cast<f16x8*>(dst + 8) = o1;
    }
    if (g == 0) {
        pm[pb * 16 + q4] = m;
        pl[pb * 16 + q4] = l;
    }
}

// ---------------------------------------------------------------------------
// merge: combine active segs per 16q tile -> final O (fp32).  exp2 domain.
// ---------------------------------------------------------------------------
__global__ __launch_bounds__(256) void merge_k(
    const f16_t* __restrict__ pO, const float* __restrict__ pm,
    const float* __restrict__ pl, float* __restrict__ O)
{
    const int tile = blockIdx.x, b = blockIdx.y;   // 256 tiles of 16 queries
    const int C = (tile >> 2) + 1;
    const int S = (C < SEGS) ? C : SEGS;
    const int t = threadIdx.x;
    const int q = t >> 4, dc = (t & 15) << 2;
    const long pb = ((long)b * 256 + tile) * SEGS;

    float mstar = -1e30f;
    for (int s = 0; s < S; ++s) mstar = fmaxf(mstar, pm[(pb + s) * 16 + q]);
    float L = 0.f;
    float o[4] = {0.f, 0.f, 0.f, 0.f};
    for (int s = 0; s < S; ++s) {
        const float ws = __builtin_exp2f(pm[(pb + s) * 16 + q] - mstar) * pl[(pb + s) * 16 + q];
        L += ws;
        const f16_t* src = pO + ((pb + s) * 16 + q) * 64 + dc;
        f16x4 a = *reinterpret_cast<const f16x4*>(src);
        #pragma unroll
        for (int i = 0; i < 4; ++i) o[i] += ws * (float)a[i];
    }
    const float inv = 1.0f / L;
    f32x4 v = {o[0] * inv, o[1] * inv, o[2] * inv, o[3] * inv};
    *reinterpret_cast<f32x4*>(O + ((long)b * TSEQ + tile * 16 + q) * 64 + dc) = v;
}

extern "C" void kernel_launch(void* const* d_in, const int* in_sizes, int n_in,
                              void* d_out, int out_size, void* d_ws, size_t ws_size,
                              hipStream_t stream)
{
    const float* X  = (const float*)d_in[0];
    const float* Wq = (const float*)d_in[1];
    const float* Wk = (const float*)d_in[2];
    const float* Wv = (const float*)d_in[3];
    float* O = (float*)d_out;

    char* ws = (char*)d_ws;
    size_t off = 0;
    bf16_t* wT = (bf16_t*)(ws + off); off += 192 * 1024 * sizeof(bf16_t);
    bf16_t* qh = (bf16_t*)(ws + off); off += 8192L * 64 * sizeof(bf16_t);
    bf16_t* kh = (bf16_t*)(ws + off); off += 8192L * 64 * sizeof(bf16_t);
    bf16_t* vt = (bf16_t*)(ws + off); off += 64L * 8192 * sizeof(bf16_t);
    f16_t*  pO = (f16_t*)(ws + off);  off += 2L * 256 * SEGS * 16 * 64 * sizeof(f16_t);
    float*  pm = (float*)(ws + off);  off += 2L * 256 * SEGS * 16 * sizeof(float);
    float*  pl = (float*)(ws + off);  off += 2L * 256 * SEGS * 16 * sizeof(float);

    wsplit_k <<<48, 256, 0, stream>>>(Wq, Wk, Wv, wT);
    proj_mfma<<<512, 256, 0, stream>>>(X, wT, qh, kh, vt);
    attn_mfma<<<dim3(4096), 64, 0, stream>>>(qh, kh, vt, pO, pm, pl);
    merge_k  <<<dim3(256, 2), 256, 0, stream>>>(pO, pm, pl, O);
}

// Round 9
// 93.336 us; speedup vs baseline: 1.4280x; 1.4280x over previous
//
#include <hip/hip_runtime.h>

typedef __bf16 bf16_t;
typedef __bf16 bf16x8 __attribute__((ext_vector_type(8)));
typedef __bf16 bf16x4 __attribute__((ext_vector_type(4)));
typedef float  f32x4  __attribute__((ext_vector_type(4)));
typedef _Float16 f16_t;
typedef _Float16 f16x8 __attribute__((ext_vector_type(8)));
typedef _Float16 f16x4 __attribute__((ext_vector_type(4)));

#define TSEQ 4096
#define SEGS 8

// lgkm-only barrier (proj): in-flight global prefetches survive it.
__device__ __forceinline__ void barrier_lds() {
    __builtin_amdgcn_sched_barrier(0);
    asm volatile("s_waitcnt lgkmcnt(0)" ::: "memory");
    __builtin_amdgcn_s_barrier();
    __builtin_amdgcn_sched_barrier(0);
}

// ---------------------------------------------------------------------------
// wsplit: W[1024][64] (q,k,v fp32) -> wT[192][1024] bf16 (transposed).
// Wq pre-scaled by 0.125*log2(e) so attention scores land in exp2 domain.
// ---------------------------------------------------------------------------
__global__ __launch_bounds__(256) void wsplit_k(
    const float* __restrict__ Wq, const float* __restrict__ Wk,
    const float* __restrict__ Wv, bf16_t* __restrict__ wT)
{
    __shared__ bf16_t th[64][72];
    const int mat = blockIdx.x >> 4;
    const int kb  = (blockIdx.x & 15) * 64;
    const float* W = (mat == 0) ? Wq : ((mat == 1) ? Wk : Wv);
    const float scale = (mat == 0) ? 0.18033688011112042f : 1.0f;
    const int t  = threadIdx.x;
    const int kl = t >> 2;
    const int dc = (t & 3) * 16;
    #pragma unroll
    for (int i = 0; i < 4; ++i) {
        float4 v = *reinterpret_cast<const float4*>(W + (long)(kb + kl) * 64 + dc + 4 * i);
        th[dc + 4*i + 0][kl] = (bf16_t)(v.x * scale);
        th[dc + 4*i + 1][kl] = (bf16_t)(v.y * scale);
        th[dc + 4*i + 2][kl] = (bf16_t)(v.z * scale);
        th[dc + 4*i + 3][kl] = (bf16_t)(v.w * scale);
    }
    __syncthreads();
    const int d  = t >> 2;
    const int kc = (t & 3) * 16;
    bf16x8 a0 = *reinterpret_cast<const bf16x8*>(&th[d][kc]);
    bf16x8 a1 = *reinterpret_cast<const bf16x8*>(&th[d][kc + 8]);
    long o = (long)(mat * 64 + d) * 1024 + kb + kc;
    *reinterpret_cast<bf16x8*>(wT + o)     = a0;
    *reinterpret_cast<bf16x8*>(wT + o + 8) = a1;
}

// ---------------------------------------------------------------------------
// proj: [8192][192] = X @ W^T.  512 blocks = 128 row-groups x 4 N-blocks;
// 4 waves M-split.  X direct-to-frags (2-step ping-pong), W dbuf in LDS.
// In-loop barriers are lgkm-only so X/W prefetches stay in flight.
// ---------------------------------------------------------------------------
__global__ __launch_bounds__(256, 2) void proj_mfma(
    const float* __restrict__ X, const bf16_t* __restrict__ wT,
    bf16_t* __restrict__ qh, bf16_t* __restrict__ kh, bf16_t* __restrict__ vt)
{
    __shared__ __align__(16) unsigned char smem[13824];
    bf16_t (*wl)[48][72] = reinterpret_cast<bf16_t(*)[48][72]>(smem);   // [2][48][72]
    float  (*vtl)[68]    = reinterpret_cast<float(*)[68]>(smem);        // [48][68] (union)

    const int tid = threadIdx.x, lane = tid & 63;
    const int mw  = tid >> 6;
    const int q4 = lane & 15, g = lane >> 4;
    const int bx = blockIdx.x;
    const int rg = bx & 127, nb = bx >> 7;
    const long R0 = (long)rg * 64;

    const float* xrow = X + (R0 + 16 * mw + q4) * 1024 + 8 * g;

    const int wrow = tid >> 2, c16 = (tid & 3) * 16;
    const bf16_t* wsrc = wT + (long)(48 * nb + wrow) * 1024 + c16;
    const bool wact = (tid < 192);

    bf16x8 wr0, wr1;
    float4 xE[4], xO[4];
    f32x4 acc[3] = {};

    auto loadW = [&](int t) {
        if (wact) {
            wr0 = *reinterpret_cast<const bf16x8*>(wsrc + t * 64);
            wr1 = *reinterpret_cast<const bf16x8*>(wsrc + t * 64 + 8);
        }
    };
    auto writeW = [&](int buf) {
        if (wact) {
            *reinterpret_cast<bf16x8*>(&wl[buf][wrow][c16])     = wr0;
            *reinterpret_cast<bf16x8*>(&wl[buf][wrow][c16 + 8]) = wr1;
        }
    };
    auto loadX = [&](int t, float4 (&xc)[4]) {
        xc[0] = *reinterpret_cast<const float4*>(xrow + t * 64);
        xc[1] = *reinterpret_cast<const float4*>(xrow + t * 64 + 4);
        xc[2] = *reinterpret_cast<const float4*>(xrow + t * 64 + 32);
        xc[3] = *reinterpret_cast<const float4*>(xrow + t * 64 + 36);
    };

    loadW(0); writeW(0);
    loadW(1);
    loadX(0, xE); loadX(1, xO);
    asm volatile("" ::: "memory");
    barrier_lds();

    auto stepf = [&](int t, float4 (&xc)[4]) {
        if (t + 1 < 16) {
            writeW((t + 1) & 1);
            loadW(t + 2 < 16 ? t + 2 : 15);
        }
        bf16x8 a0 = {(bf16_t)xc[0].x, (bf16_t)xc[0].y, (bf16_t)xc[0].z, (bf16_t)xc[0].w,
                     (bf16_t)xc[1].x, (bf16_t)xc[1].y, (bf16_t)xc[1].z, (bf16_t)xc[1].w};
        bf16x8 a1 = {(bf16_t)xc[2].x, (bf16_t)xc[2].y, (bf16_t)xc[2].z, (bf16_t)xc[2].w,
                     (bf16_t)xc[3].x, (bf16_t)xc[3].y, (bf16_t)xc[3].z, (bf16_t)xc[3].w};
        if (t + 2 < 16) loadX(t + 2, xc);
        asm volatile("" ::: "memory");
        __builtin_amdgcn_s_setprio(1);
        #pragma unroll
        for (int j = 0; j < 3; ++j) {
            bf16x8 b0 = *reinterpret_cast<const bf16x8*>(&wl[t & 1][16 * j + q4][8 * g]);
            bf16x8 b1 = *reinterpret_cast<const bf16x8*>(&wl[t & 1][16 * j + q4][8 * g + 32]);
            acc[j] = __builtin_amdgcn_mfma_f32_16x16x32_bf16(a0, b0, acc[j], 0, 0, 0);
            acc[j] = __builtin_amdgcn_mfma_f32_16x16x32_bf16(a1, b1, acc[j], 0, 0, 0);
        }
        __builtin_amdgcn_s_setprio(0);
        barrier_lds();
    };
    #pragma unroll
    for (int tt = 0; tt < 16; tt += 2) { stepf(tt, xE); stepf(tt + 1, xO); }

    const int vbase = (nb == 2) ? 0 : 16;
    #pragma unroll
    for (int j = 0; j < 3; ++j) {
        const int nt = 3 * nb + j;
        #pragma unroll
        for (int r = 0; r < 4; ++r) {
            const long row = R0 + 16 * mw + 4 * g + r;
            const float vv = acc[j][r];
            if (nt < 4)      qh[row * 64 + nt * 16 + q4] = (bf16_t)vv;
            else if (nt < 8) kh[row * 64 + (nt - 4) * 16 + q4] = (bf16_t)vv;
            else             vtl[(nt - 8) * 16 + q4 - vbase][16 * mw + 4 * g + r] = vv;
        }
    }
    if (nb >= 2) {
        barrier_lds();
        const int nd = (nb == 2) ? 16 : 48;
        const int dl = tid >> 2, cc = (tid & 3) * 16;
        if (dl < nd) {
            bf16x8 o0, o1;
            #pragma unroll
            for (int i = 0; i < 8; ++i) {
                o0[i] = (bf16_t)vtl[dl][cc + i];
                o1[i] = (bf16_t)vtl[dl][cc + 8 + i];
            }
            bf16_t* dst = vt + (long)(vbase + dl) * 8192 + R0 + cc;
            *reinterpret_cast<bf16x8*>(dst)     = o0;
            *reinterpret_cast<bf16x8*>(dst + 8) = o1;
        }
    }
}

// ---------------------------------------------------------------------------
// attn: flash, 1-wave blocks (16 queries), self-paced, no barriers.
// Register budget engineered under the 128-VGPR cap of launch_bounds(64,4):
//  - NO K-prefetch (K regs die at QK; V loads reuse them, issued right
//    after QK so L2 latency hides under softmax + 4-waves/SIMD TLP)
//  - persistent row POINTERS (4 K + 4 V) advanced by constants; every load
//    is base + {0,64B} immediate -> no per-iter 64-bit address math.
// Seg-major order: co-resident blocks walk the same chunk -> L1 sharing.
// ---------------------------------------------------------------------------
__global__ __launch_bounds__(64, 4) void attn_mfma(
    const bf16_t* __restrict__ qh, const bf16_t* __restrict__ kh,
    const bf16_t* __restrict__ vt,
    f16_t* __restrict__ pO, float* __restrict__ pm, float* __restrict__ pl)
{
    __shared__ __align__(16) unsigned char smem[2304];
    bf16_t (*P)[16][8] = reinterpret_cast<bf16_t(*)[16][8]>(smem);  // [8][16][8]
    f16_t  (*ot)[72]   = reinterpret_cast<f16_t(*)[72]>(smem);      // [16][72] overlay

    const int lane = threadIdx.x;
    const int q4 = lane & 15, g = lane >> 4;
    const int bx = blockIdx.x;
    const int b = bx >> 11;
    const int inner = bx & 2047;
    const int seg = inner >> 8;             // seg-major
    const int qi  = 255 - (inner & 255);    // heavy tiles first within seg
    const int C = (qi >> 2) + 1;            // causal 64-key chunk count
    if (seg >= C) return;
    const long base = (long)b * TSEQ;
    const int r0 = qi << 4;
    const int rq = r0 + q4;

    const bf16_t* qr = qh + (base + r0 + q4) * 64 + 8 * g;
    const bf16x8 qf0 = *reinterpret_cast<const bf16x8*>(qr);
    const bf16x8 qf1 = *reinterpret_cast<const bf16x8*>(qr + 32);

    // persistent row pointers, advanced by constants each chunk
    const bf16_t* kp0 = kh + (base + (seg << 6) +  0 + q4) * 64 + 8 * g;
    const bf16_t* kp1 = kh + (base + (seg << 6) + 16 + q4) * 64 + 8 * g;
    const bf16_t* kp2 = kh + (base + (seg << 6) + 32 + q4) * 64 + 8 * g;
    const bf16_t* kp3 = kh + (base + (seg << 6) + 48 + q4) * 64 + 8 * g;
    const bf16_t* vp0 = vt + (long)( 0 + q4) * 8192 + base + (seg << 6) + 8 * g;
    const bf16_t* vp1 = vt + (long)(16 + q4) * 8192 + base + (seg << 6) + 8 * g;
    const bf16_t* vp2 = vt + (long)(32 + q4) * 8192 + base + (seg << 6) + 8 * g;
    const bf16_t* vp3 = vt + (long)(48 + q4) * 8192 + base + (seg << 6) + 8 * g;
    const long KADV = (long)SEGS * 64 * 64;   // elements per chunk stride (K rows)
    const long VADV = (long)SEGS * 64;        // elements per chunk stride (V cols)

    float m = -1e30f, l = 0.f;
    f32x4 oacc0 = {}, oacc1 = {}, oacc2 = {}, oacc3 = {};

    for (int c = seg; c < C; c += SEGS) {
        const int kb = c << 6;

        // ---- K loads (base + {0,64B} immediates only)
        bf16x8 ku0 = *reinterpret_cast<const bf16x8*>(kp0);
        bf16x8 kw0 = *reinterpret_cast<const bf16x8*>(kp0 + 32);
        bf16x8 ku1 = *reinterpret_cast<const bf16x8*>(kp1);
        bf16x8 kw1 = *reinterpret_cast<const bf16x8*>(kp1 + 32);
        bf16x8 ku2 = *reinterpret_cast<const bf16x8*>(kp2);
        bf16x8 kw2 = *reinterpret_cast<const bf16x8*>(kp2 + 32);
        bf16x8 ku3 = *reinterpret_cast<const bf16x8*>(kp3);
        bf16x8 kw3 = *reinterpret_cast<const bf16x8*>(kp3 + 32);
        kp0 += KADV; kp1 += KADV; kp2 += KADV; kp3 += KADV;

        // ---- QK^T (swapped): S^T[key][query]
        f32x4 s0 = {}, s1 = {}, s2 = {}, s3 = {};
        s0 = __builtin_amdgcn_mfma_f32_16x16x32_bf16(ku0, qf0, s0, 0, 0, 0);
        s0 = __builtin_amdgcn_mfma_f32_16x16x32_bf16(kw0, qf1, s0, 0, 0, 0);
        s1 = __builtin_amdgcn_mfma_f32_16x16x32_bf16(ku1, qf0, s1, 0, 0, 0);
        s1 = __builtin_amdgcn_mfma_f32_16x16x32_bf16(kw1, qf1, s1, 0, 0, 0);
        s2 = __builtin_amdgcn_mfma_f32_16x16x32_bf16(ku2, qf0, s2, 0, 0, 0);
        s2 = __builtin_amdgcn_mfma_f32_16x16x32_bf16(kw2, qf1, s2, 0, 0, 0);
        s3 = __builtin_amdgcn_mfma_f32_16x16x32_bf16(ku3, qf0, s3, 0, 0, 0);
        s3 = __builtin_amdgcn_mfma_f32_16x16x32_bf16(kw3, qf1, s3, 0, 0, 0);

        // ---- V loads: K regs now dead -> reuse; latency hides under softmax
        bf16x8 vu0 = *reinterpret_cast<const bf16x8*>(vp0);
        bf16x8 vw0 = *reinterpret_cast<const bf16x8*>(vp0 + 32);
        bf16x8 vu1 = *reinterpret_cast<const bf16x8*>(vp1);
        bf16x8 vw1 = *reinterpret_cast<const bf16x8*>(vp1 + 32);
        bf16x8 vu2 = *reinterpret_cast<const bf16x8*>(vp2);
        bf16x8 vw2 = *reinterpret_cast<const bf16x8*>(vp2 + 32);
        bf16x8 vu3 = *reinterpret_cast<const bf16x8*>(vp3);
        bf16x8 vw3 = *reinterpret_cast<const bf16x8*>(vp3 + 32);
        vp0 += VADV; vp1 += VADV; vp2 += VADV; vp3 += VADV;
        __builtin_amdgcn_sched_barrier(0);   // pin V issue before softmax

        // ---- causal mask: diagonal chunk only (uniform branch)
        if (c == C - 1) {
            const int kk = kb + 4 * g;
            #pragma unroll
            for (int r = 0; r < 4; ++r) {
                if (kk +  0 + r > rq) s0[r] = -1e30f;
                if (kk + 16 + r > rq) s1[r] = -1e30f;
                if (kk + 32 + r > rq) s2[r] = -1e30f;
                if (kk + 48 + r > rq) s3[r] = -1e30f;
            }
        }

        // ---- per-query max
        float mx = s0[0];
        #pragma unroll
        for (int r = 0; r < 4; ++r) {
            mx = fmaxf(mx, s0[r]); mx = fmaxf(mx, s1[r]);
            mx = fmaxf(mx, s2[r]); mx = fmaxf(mx, s3[r]);
        }
        mx = fmaxf(mx, __shfl_xor(mx, 16));
        mx = fmaxf(mx, __shfl_xor(mx, 32));

        // ---- exp2 in place; exact defer-rescale when max didn't grow
        float lsum = 0.f;
        if (__all(mx <= m)) {
            #pragma unroll
            for (int r = 0; r < 4; ++r) {
                s0[r] = __builtin_exp2f(s0[r] - m); lsum += s0[r];
                s1[r] = __builtin_exp2f(s1[r] - m); lsum += s1[r];
                s2[r] = __builtin_exp2f(s2[r] - m); lsum += s2[r];
                s3[r] = __builtin_exp2f(s3[r] - m); lsum += s3[r];
            }
        } else {
            const float mnew = fmaxf(m, mx);
            const float alpha = __builtin_exp2f(m - mnew);
            m = mnew;
            #pragma unroll
            for (int r = 0; r < 4; ++r) {
                s0[r] = __builtin_exp2f(s0[r] - mnew); lsum += s0[r];
                s1[r] = __builtin_exp2f(s1[r] - mnew); lsum += s1[r];
                s2[r] = __builtin_exp2f(s2[r] - mnew); lsum += s2[r];
                s3[r] = __builtin_exp2f(s3[r] - mnew); lsum += s3[r];
            }
            oacc0 *= alpha; oacc1 *= alpha; oacc2 *= alpha; oacc3 *= alpha;
            l *= alpha;
        }
        lsum += __shfl_xor(lsum, 16);
        lsum += __shfl_xor(lsum, 32);
        l += lsum;

        // ---- pack P -> per-wave LDS tile (same wave; lgkm only, no barrier)
        {
            const int ki = (g & 1) << 2, cb = g >> 1;
            bf16x4 h0 = {(bf16_t)s0[0], (bf16_t)s0[1], (bf16_t)s0[2], (bf16_t)s0[3]};
            bf16x4 h1 = {(bf16_t)s1[0], (bf16_t)s1[1], (bf16_t)s1[2], (bf16_t)s1[3]};
            bf16x4 h2 = {(bf16_t)s2[0], (bf16_t)s2[1], (bf16_t)s2[2], (bf16_t)s2[3]};
            bf16x4 h3 = {(bf16_t)s3[0], (bf16_t)s3[1], (bf16_t)s3[2], (bf16_t)s3[3]};
            *reinterpret_cast<bf16x4*>(&P[0 + cb][q4][ki]) = h0;
            *reinterpret_cast<bf16x4*>(&P[2 + cb][q4][ki]) = h1;
            *reinterpret_cast<bf16x4*>(&P[4 + cb][q4][ki]) = h2;
            *reinterpret_cast<bf16x4*>(&P[6 + cb][q4][ki]) = h3;
        }
        bf16x8 ph0 = *reinterpret_cast<const bf16x8*>(&P[g][q4][0]);
        bf16x8 ph1 = *reinterpret_cast<const bf16x8*>(&P[4 + g][q4][0]);

        // ---- PV: O^T += V^T x P^T (V issued before softmax)
        oacc0 = __builtin_amdgcn_mfma_f32_16x16x32_bf16(vu0, ph0, oacc0, 0, 0, 0);
        oacc0 = __builtin_amdgcn_mfma_f32_16x16x32_bf16(vw0, ph1, oacc0, 0, 0, 0);
        oacc1 = __builtin_amdgcn_mfma_f32_16x16x32_bf16(vu1, ph0, oacc1, 0, 0, 0);
        oacc1 = __builtin_amdgcn_mfma_f32_16x16x32_bf16(vw1, ph1, oacc1, 0, 0, 0);
        oacc2 = __builtin_amdgcn_mfma_f32_16x16x32_bf16(vu2, ph0, oacc2, 0, 0, 0);
        oacc2 = __builtin_amdgcn_mfma_f32_16x16x32_bf16(vw2, ph1, oacc2, 0, 0, 0);
        oacc3 = __builtin_amdgcn_mfma_f32_16x16x32_bf16(vu3, ph0, oacc3, 0, 0, 0);
        oacc3 = __builtin_amdgcn_mfma_f32_16x16x32_bf16(vw3, ph1, oacc3, 0, 0, 0);
    }

    // ---- epilogue: normalize, transpose via LDS (overlays P), store f16
    const float invl = 1.0f / l;
    #pragma unroll
    for (int r = 0; r < 4; ++r) {
        ot[q4][ 0 + 4 * g + r] = (f16_t)(oacc0[r] * invl);
        ot[q4][16 + 4 * g + r] = (f16_t)(oacc1[r] * invl);
        ot[q4][32 + 4 * g + r] = (f16_t)(oacc2[r] * invl);
        ot[q4][48 + 4 * g + r] = (f16_t)(oacc3[r] * invl);
    }

    const long pb = ((long)b * 256 + qi) * SEGS + seg;
    {
        const int q  = lane >> 2;
        const int dc = (lane & 3) << 4;
        f16x8 o0 = *reinterpret_cast<const f16x8*>(&ot[q][dc]);
        f16x8 o1 = *reinterpret_cast<const f16x8*>(&ot[q][dc + 8]);
        f16_t* dst = pO + (pb * 16 + q) * 64 + dc;
        *reinterpret_cast<f16x8*>(dst)     = o0;
        *reinterpret_cast<f16x8*>(dst + 8) = o1;
    }
    if (g == 0) {
        pm[pb * 16 + q4] = m;
        pl[pb * 16 + q4] = l;
    }
}

// ---------------------------------------------------------------------------
// merge: combine active segs per 16q tile -> final O (fp32).  exp2 domain.
// ---------------------------------------------------------------------------
__global__ __launch_bounds__(256) void merge_k(
    const f16_t* __restrict__ pO, const float* __restrict__ pm,
    const float* __restrict__ pl, float* __restrict__ O)
{
    const int tile = blockIdx.x, b = blockIdx.y;   // 256 tiles of 16 queries
    const int C = (tile >> 2) + 1;
    const int S = (C < SEGS) ? C : SEGS;
    const int t = threadIdx.x;
    const int q = t >> 4, dc = (t & 15) << 2;
    const long pb = ((long)b * 256 + tile) * SEGS;

    float mstar = -1e30f;
    for (int s = 0; s < S; ++s) mstar = fmaxf(mstar, pm[(pb + s) * 16 + q]);
    float L = 0.f;
    float o[4] = {0.f, 0.f, 0.f, 0.f};
    for (int s = 0; s < S; ++s) {
        const float ws = __builtin_exp2f(pm[(pb + s) * 16 + q] - mstar) * pl[(pb + s) * 16 + q];
        L += ws;
        const f16_t* src = pO + ((pb + s) * 16 + q) * 64 + dc;
        f16x4 a = *reinterpret_cast<const f16x4*>(src);
        #pragma unroll
        for (int i = 0; i < 4; ++i) o[i] += ws * (float)a[i];
    }
    const float inv = 1.0f / L;
    f32x4 v = {o[0] * inv, o[1] * inv, o[2] * inv, o[3] * inv};
    *reinterpret_cast<f32x4*>(O + ((long)b * TSEQ + tile * 16 + q) * 64 + dc) = v;
}

extern "C" void kernel_launch(void* const* d_in, const int* in_sizes, int n_in,
                              void* d_out, int out_size, void* d_ws, size_t ws_size,
                              hipStream_t stream)
{
    const float* X  = (const float*)d_in[0];
    const float* Wq = (const float*)d_in[1];
    const float* Wk = (const float*)d_in[2];
    const float* Wv = (const float*)d_in[3];
    float* O = (float*)d_out;

    char* ws = (char*)d_ws;
    size_t off = 0;
    bf16_t* wT = (bf16_t*)(ws + off); off += 192 * 1024 * sizeof(bf16_t);
    bf16_t* qh = (bf16_t*)(ws + off); off += 8192L * 64 * sizeof(bf16_t);
    bf16_t* kh = (bf16_t*)(ws + off); off += 8192L * 64 * sizeof(bf16_t);
    bf16_t* vt = (bf16_t*)(ws + off); off += 64L * 8192 * sizeof(bf16_t);
    f16_t*  pO = (f16_t*)(ws + off);  off += 2L * 256 * SEGS * 16 * 64 * sizeof(f16_t);
    float*  pm = (float*)(ws + off);  off += 2L * 256 * SEGS * 16 * sizeof(float);
    float*  pl = (float*)(ws + off);  off += 2L * 256 * SEGS * 16 * sizeof(float);

    wsplit_k <<<48, 256, 0, stream>>>(Wq, Wk, Wv, wT);
    proj_mfma<<<512, 256, 0, stream>>>(X, wT, qh, kh, vt);
    attn_mfma<<<dim3(4096), 64, 0, stream>>>(qh, kh, vt, pO, pm, pl);
    merge_k  <<<dim3(256, 2), 256, 0, stream>>>(pO, pm, pl, O);
}

// Round 10
// 57.800 us; speedup vs baseline: 2.3059x; 1.6148x over previous
//
#include <hip/hip_runtime.h>

typedef __bf16 bf16_t;
typedef __bf16 bf16x8 __attribute__((ext_vector_type(8)));
typedef __bf16 bf16x4 __attribute__((ext_vector_type(4)));
typedef float  f32x4  __attribute__((ext_vector_type(4)));
typedef _Float16 f16_t;
typedef _Float16 f16x8 __attribute__((ext_vector_type(8)));

#define TSEQ 4096
#define SEGS 8

// lgkm-only barrier: in-flight global prefetches survive it.
__device__ __forceinline__ void barrier_lds() {
    __builtin_amdgcn_sched_barrier(0);
    asm volatile("s_waitcnt lgkmcnt(0)" ::: "memory");
    __builtin_amdgcn_s_barrier();
    __builtin_amdgcn_sched_barrier(0);
}

// ---------------------------------------------------------------------------
// wsplit: W[1024][64] (q,k,v fp32) -> wT[192][1024] bf16 (transposed).
// Wq pre-scaled by 0.125*log2(e) so attention scores land in exp2 domain.
// ---------------------------------------------------------------------------
__global__ __launch_bounds__(256) void wsplit_k(
    const float* __restrict__ Wq, const float* __restrict__ Wk,
    const float* __restrict__ Wv, bf16_t* __restrict__ wT)
{
    __shared__ bf16_t th[64][72];
    const int mat = blockIdx.x >> 4;
    const int kb  = (blockIdx.x & 15) * 64;
    const float* W = (mat == 0) ? Wq : ((mat == 1) ? Wk : Wv);
    const float scale = (mat == 0) ? 0.18033688011112042f : 1.0f;
    const int t  = threadIdx.x;
    const int kl = t >> 2;
    const int dc = (t & 3) * 16;
    #pragma unroll
    for (int i = 0; i < 4; ++i) {
        float4 v = *reinterpret_cast<const float4*>(W + (long)(kb + kl) * 64 + dc + 4 * i);
        th[dc + 4*i + 0][kl] = (bf16_t)(v.x * scale);
        th[dc + 4*i + 1][kl] = (bf16_t)(v.y * scale);
        th[dc + 4*i + 2][kl] = (bf16_t)(v.z * scale);
        th[dc + 4*i + 3][kl] = (bf16_t)(v.w * scale);
    }
    __syncthreads();
    const int d  = t >> 2;
    const int kc = (t & 3) * 16;
    bf16x8 a0 = *reinterpret_cast<const bf16x8*>(&th[d][kc]);
    bf16x8 a1 = *reinterpret_cast<const bf16x8*>(&th[d][kc + 8]);
    long o = (long)(mat * 64 + d) * 1024 + kb + kc;
    *reinterpret_cast<bf16x8*>(wT + o)     = a0;
    *reinterpret_cast<bf16x8*>(wT + o + 8) = a1;
}

// ---------------------------------------------------------------------------
// proj: [8192][192] = X @ W^T.  512 blocks = 256 row-groups (32 rows) x
// 2 N-blocks (96 cols).  4 waves = 2M x 2N; wave = 16 rows x 3 tiles.
// X direct-to-frags (2-step ping-pong), W (96x64/step) dbuf in LDS.
// N-blocks halved 4->2 to cut X HBM re-reads; nb-major so the pair sharing
// a row-group lands on the same XCD (bx, bx+256 -> same %8 class).
// ---------------------------------------------------------------------------
__global__ __launch_bounds__(256, 2) void proj_mfma(
    const float* __restrict__ X, const bf16_t* __restrict__ wT,
    bf16_t* __restrict__ qh, bf16_t* __restrict__ kh, bf16_t* __restrict__ vt)
{
    __shared__ __align__(16) unsigned char smem[27648];
    bf16_t (*wl)[96][72] = reinterpret_cast<bf16_t(*)[96][72]>(smem);   // [2][96][72]
    float  (*vtl)[36]    = reinterpret_cast<float(*)[36]>(smem);        // [64][36] union

    const int tid = threadIdx.x, lane = tid & 63;
    const int w   = tid >> 6;
    const int mw  = w >> 1, nw2 = w & 1;
    const int q4 = lane & 15, g = lane >> 4;
    const int bx = blockIdx.x;
    const int rg = bx & 255, nb = bx >> 8;   // nb-major
    const long R0 = (long)rg * 32;

    const float* xrow = X + (R0 + 16 * mw + q4) * 1024 + 8 * g;

    // W staging: threads 0..191: row t>>1 (0..95), k-half (t&1)*32
    const int wrow = tid >> 1, c32 = (tid & 1) * 32;
    const bf16_t* wsrc = wT + (long)(96 * nb + wrow) * 1024 + c32;
    const bool wact = (tid < 192);

    bf16x8 wr0, wr1, wr2, wr3;
    float4 xE[4], xO[4];
    f32x4 acc[3] = {};

    auto loadW = [&](int t) {
        if (wact) {
            wr0 = *reinterpret_cast<const bf16x8*>(wsrc + t * 64);
            wr1 = *reinterpret_cast<const bf16x8*>(wsrc + t * 64 + 8);
            wr2 = *reinterpret_cast<const bf16x8*>(wsrc + t * 64 + 16);
            wr3 = *reinterpret_cast<const bf16x8*>(wsrc + t * 64 + 24);
        }
    };
    auto writeW = [&](int buf) {
        if (wact) {
            *reinterpret_cast<bf16x8*>(&wl[buf][wrow][c32])      = wr0;
            *reinterpret_cast<bf16x8*>(&wl[buf][wrow][c32 + 8])  = wr1;
            *reinterpret_cast<bf16x8*>(&wl[buf][wrow][c32 + 16]) = wr2;
            *reinterpret_cast<bf16x8*>(&wl[buf][wrow][c32 + 24]) = wr3;
        }
    };
    auto loadX = [&](int t, float4 (&xc)[4]) {
        xc[0] = *reinterpret_cast<const float4*>(xrow + t * 64);
        xc[1] = *reinterpret_cast<const float4*>(xrow + t * 64 + 4);
        xc[2] = *reinterpret_cast<const float4*>(xrow + t * 64 + 32);
        xc[3] = *reinterpret_cast<const float4*>(xrow + t * 64 + 36);
    };

    loadW(0); writeW(0);
    loadW(1);
    loadX(0, xE); loadX(1, xO);
    asm volatile("" ::: "memory");
    barrier_lds();

    auto stepf = [&](int t, float4 (&xc)[4]) {
        if (t + 1 < 16) {
            writeW((t + 1) & 1);
            loadW(t + 2 < 16 ? t + 2 : 15);
        }
        bf16x8 a0 = {(bf16_t)xc[0].x, (bf16_t)xc[0].y, (bf16_t)xc[0].z, (bf16_t)xc[0].w,
                     (bf16_t)xc[1].x, (bf16_t)xc[1].y, (bf16_t)xc[1].z, (bf16_t)xc[1].w};
        bf16x8 a1 = {(bf16_t)xc[2].x, (bf16_t)xc[2].y, (bf16_t)xc[2].z, (bf16_t)xc[2].w,
                     (bf16_t)xc[3].x, (bf16_t)xc[3].y, (bf16_t)xc[3].z, (bf16_t)xc[3].w};
        if (t + 2 < 16) loadX(t + 2, xc);
        asm volatile("" ::: "memory");
        __builtin_amdgcn_s_setprio(1);
        #pragma unroll
        for (int j = 0; j < 3; ++j) {
            const int lr = (3 * nw2 + j) * 16 + q4;   // local W row 0..95
            bf16x8 b0 = *reinterpret_cast<const bf16x8*>(&wl[t & 1][lr][8 * g]);
            bf16x8 b1 = *reinterpret_cast<const bf16x8*>(&wl[t & 1][lr][8 * g + 32]);
            acc[j] = __builtin_amdgcn_mfma_f32_16x16x32_bf16(a0, b0, acc[j], 0, 0, 0);
            acc[j] = __builtin_amdgcn_mfma_f32_16x16x32_bf16(a1, b1, acc[j], 0, 0, 0);
        }
        __builtin_amdgcn_s_setprio(0);
        barrier_lds();
    };
    #pragma unroll
    for (int tt = 0; tt < 16; tt += 2) { stepf(tt, xE); stepf(tt + 1, xO); }

    // epilogue: nt<4 -> q, nt<8 -> k, else v staged in vtl for transpose
    #pragma unroll
    for (int j = 0; j < 3; ++j) {
        const int nt = 6 * nb + 3 * nw2 + j;
        #pragma unroll
        for (int r = 0; r < 4; ++r) {
            const long row = R0 + 16 * mw + 4 * g + r;
            const float vv = acc[j][r];
            if (nt < 4)      qh[row * 64 + nt * 16 + q4] = (bf16_t)vv;
            else if (nt < 8) kh[row * 64 + (nt - 4) * 16 + q4] = (bf16_t)vv;
            else             vtl[(nt - 8) * 16 + q4][16 * mw + 4 * g + r] = vv;
        }
    }
    if (nb == 1) {   // nb=1 computed nt 8..11 = all of v
        barrier_lds();
        const int d = tid >> 2, c8 = (tid & 3) * 8;
        bf16x8 o;
        #pragma unroll
        for (int i = 0; i < 8; ++i) o[i] = (bf16_t)vtl[d][c8 + i];
        *reinterpret_cast<bf16x8*>(vt + (long)d * 8192 + R0 + c8) = o;
    }
}

// ---------------------------------------------------------------------------
// attn (r6 version, best measured ~20us): flash, block = 64 queries (4 waves
// M-split), seg round-robin causal split.  K/V double-buffered in LDS,
// staged T14 (loads one chunk early); in-loop barrier lgkm-only.  exp2.
// ---------------------------------------------------------------------------
__global__ __launch_bounds__(256, 3) void attn_mfma(
    const bf16_t* __restrict__ qh, const bf16_t* __restrict__ kh,
    const bf16_t* __restrict__ vt,
    f16_t* __restrict__ pO, float* __restrict__ pm, float* __restrict__ pl)
{
    __shared__ __align__(16) unsigned char smem[46080];
    bf16_t (*kl)[64][72]  = reinterpret_cast<bf16_t(*)[64][72]>(smem);           // [2]
    bf16_t (*vl)[64][72]  = reinterpret_cast<bf16_t(*)[64][72]>(smem + 18432);   // [2]
    bf16_t (*P)[8][16][8] = reinterpret_cast<bf16_t(*)[8][16][8]>(smem + 36864); // [4]
    f16_t  (*ot)[16][72]  = reinterpret_cast<f16_t(*)[16][72]>(smem + 36864);    // [4] union

    const int tid = threadIdx.x, lane = tid & 63, w = tid >> 6;
    const int q4 = lane & 15, g = lane >> 4;
    const int bx = blockIdx.x, b = blockIdx.y;
    const int tile = 63 - (bx >> 3);     // heavy tiles first
    const int seg  = bx & 7;
    const int C = tile + 1;
    if (seg >= C) return;
    const long base = (long)b * TSEQ;
    const int r0 = tile * 64 + 16 * w;

    const bf16_t* qr = qh + (base + r0 + q4) * 64 + 8 * g;
    const bf16x8 qf0 = *reinterpret_cast<const bf16x8*>(qr);
    const bf16x8 qf1 = *reinterpret_cast<const bf16x8*>(qr + 32);

    const int srow = tid >> 2, sc = (tid & 3) * 16;
    const bf16_t* ksrc = kh + (base + srow) * 64 + sc;
    const bf16_t* vsrc = vt + (long)srow * 8192 + base + sc;
    bf16x8 kr0, kr1, vr0, vr1;
    auto loadKV = [&](int kb) {
        kr0 = *reinterpret_cast<const bf16x8*>(ksrc + (long)kb * 64);
        kr1 = *reinterpret_cast<const bf16x8*>(ksrc + (long)kb * 64 + 8);
        vr0 = *reinterpret_cast<const bf16x8*>(vsrc + kb);
        vr1 = *reinterpret_cast<const bf16x8*>(vsrc + kb + 8);
    };
    auto writeKV = [&](int buf) {
        *reinterpret_cast<bf16x8*>(&kl[buf][srow][sc])     = kr0;
        *reinterpret_cast<bf16x8*>(&kl[buf][srow][sc + 8]) = kr1;
        *reinterpret_cast<bf16x8*>(&vl[buf][srow][sc])     = vr0;
        *reinterpret_cast<bf16x8*>(&vl[buf][srow][sc + 8]) = vr1;
    };

    float m = -1e30f, l = 0.f;
    f32x4 oacc[4] = {};

    loadKV(seg << 6);
    writeKV(0);
    { int c1 = seg + SEGS; loadKV((c1 < C ? c1 : seg) << 6); }
    asm volatile("" ::: "memory");
    barrier_lds();

    int i = 0;
    for (int c = seg; c < C; c += SEGS, ++i) {
        const int buf = i & 1;
        if (c + SEGS < C) {
            writeKV(buf ^ 1);
            int cn = c + 2 * SEGS;
            loadKV((cn < C ? cn : c + SEGS) << 6);
            asm volatile("" ::: "memory");
        }
        const int kb = c << 6;

        f32x4 sacc[4];
        __builtin_amdgcn_s_setprio(1);
        #pragma unroll
        for (int kt = 0; kt < 4; ++kt) {
            bf16x8 kf0 = *reinterpret_cast<const bf16x8*>(&kl[buf][kt * 16 + q4][8 * g]);
            bf16x8 kf1 = *reinterpret_cast<const bf16x8*>(&kl[buf][kt * 16 + q4][8 * g + 32]);
            f32x4 a = {};
            a = __builtin_amdgcn_mfma_f32_16x16x32_bf16(kf0, qf0, a, 0, 0, 0);
            a = __builtin_amdgcn_mfma_f32_16x16x32_bf16(kf1, qf1, a, 0, 0, 0);
            sacc[kt] = a;
        }
        __builtin_amdgcn_s_setprio(0);

        float p[16];
        const bool diag = (c == C - 1);
        float mx = -1e30f;
        #pragma unroll
        for (int kt = 0; kt < 4; ++kt)
            #pragma unroll
            for (int r = 0; r < 4; ++r) {
                float sv = sacc[kt][r];
                if (diag && (kb + kt * 16 + 4 * g + r > r0 + q4)) sv = -1e30f;
                p[kt * 4 + r] = sv;
                mx = fmaxf(mx, sv);
            }
        mx = fmaxf(mx, __shfl_xor(mx, 16));
        mx = fmaxf(mx, __shfl_xor(mx, 32));
        const float mnew = fmaxf(m, mx);
        const float alpha = __builtin_exp2f(m - mnew);
        m = mnew;
        float lsum = 0.f;
        #pragma unroll
        for (int ii = 0; ii < 16; ++ii) { p[ii] = __builtin_exp2f(p[ii] - mnew); lsum += p[ii]; }
        lsum += __shfl_xor(lsum, 16);
        lsum += __shfl_xor(lsum, 32);
        l = l * alpha + lsum;
        #pragma unroll
        for (int dt = 0; dt < 4; ++dt) oacc[dt] *= alpha;

        #pragma unroll
        for (int kt = 0; kt < 4; ++kt) {
            const int cb = 2 * kt + (g >> 1);
            const int ki = (g & 1) << 2;
            bf16x4 hv = {(bf16_t)p[4*kt+0], (bf16_t)p[4*kt+1],
                         (bf16_t)p[4*kt+2], (bf16_t)p[4*kt+3]};
            *reinterpret_cast<bf16x4*>(&P[w][cb][q4][ki]) = hv;
        }
        bf16x8 ph0 = *reinterpret_cast<const bf16x8*>(&P[w][g][q4][0]);
        bf16x8 ph1 = *reinterpret_cast<const bf16x8*>(&P[w][4 + g][q4][0]);
        __builtin_amdgcn_s_setprio(1);
        #pragma unroll
        for (int dt = 0; dt < 4; ++dt) {
            bf16x8 va0 = *reinterpret_cast<const bf16x8*>(&vl[buf][dt * 16 + q4][8 * g]);
            bf16x8 va1 = *reinterpret_cast<const bf16x8*>(&vl[buf][dt * 16 + q4][8 * g + 32]);
            oacc[dt] = __builtin_amdgcn_mfma_f32_16x16x32_bf16(va0, ph0, oacc[dt], 0, 0, 0);
            oacc[dt] = __builtin_amdgcn_mfma_f32_16x16x32_bf16(va1, ph1, oacc[dt], 0, 0, 0);
        }
        __builtin_amdgcn_s_setprio(0);
        barrier_lds();
    }

    const float invl = 1.0f / l;
    #pragma unroll
    for (int dt = 0; dt < 4; ++dt)
        #pragma unroll
        for (int r = 0; r < 4; ++r)
            ot[w][q4][dt * 16 + 4 * g + r] = (f16_t)(oacc[dt][r] * invl);

    const long pbase = (((long)b * 64 + tile) * SEGS + seg) * 64;
    {
        const int q  = lane >> 2;
        const int dc = (lane & 3) * 16;
        f16x8 o0 = *reinterpret_cast<const f16x8*>(&ot[w][q][dc]);
        f16x8 o1 = *reinterpret_cast<const f16x8*>(&ot[w][q][dc + 8]);
        f16_t* dst = pO + (pbase + 16 * w + q) * 64 + dc;
        *reinterpret_cast<f16x8*>(dst)     = o0;
        *reinterpret_cast<f16x8*>(dst + 8) = o1;
    }
    if (g == 0) {
        pm[pbase + 16 * w + q4] = m;
        pl[pbase + 16 * w + q4] = l;
    }
}

// ---------------------------------------------------------------------------
// merge: combine active segs per 64q tile -> final O (fp32).  exp2 domain.
// ---------------------------------------------------------------------------
__global__ __launch_bounds__(256) void merge_k(
    const f16_t* __restrict__ pO, const float* __restrict__ pm,
    const float* __restrict__ pl, float* __restrict__ O)
{
    const int tile = blockIdx.x, b = blockIdx.y;
    const int C = tile + 1;
    const int S = (C < SEGS) ? C : SEGS;
    const int t = threadIdx.x;
    const int q = t >> 2, dc = (t & 3) * 16;
    const long pb = ((long)b * 64 + tile) * SEGS;

    float mstar = -1e30f;
    for (int s = 0; s < S; ++s) mstar = fmaxf(mstar, pm[(pb + s) * 64 + q]);
    float L = 0.f;
    float o[16];
    #pragma unroll
    for (int i = 0; i < 16; ++i) o[i] = 0.f;
    for (int s = 0; s < S; ++s) {
        const float ws = __builtin_exp2f(pm[(pb + s) * 64 + q] - mstar) * pl[(pb + s) * 64 + q];
        L += ws;
        const f16_t* src = pO + ((pb + s) * 64 + q) * 64 + dc;
        f16x8 a0 = *reinterpret_cast<const f16x8*>(src);
        f16x8 a1 = *reinterpret_cast<const f16x8*>(src + 8);
        #pragma unroll
        for (int i = 0; i < 8; ++i) {
            o[i]     += ws * (float)a0[i];
            o[8 + i] += ws * (float)a1[i];
        }
    }
    const float inv = 1.0f / L;
    float* dst = O + ((long)b * TSEQ + tile * 64 + q) * 64 + dc;
    #pragma unroll
    for (int i = 0; i < 4; ++i) {
        f32x4 v = {o[4*i] * inv, o[4*i+1] * inv, o[4*i+2] * inv, o[4*i+3] * inv};
        *reinterpret_cast<f32x4*>(dst + 4 * i) = v;
    }
}

extern "C" void kernel_launch(void* const* d_in, const int* in_sizes, int n_in,
                              void* d_out, int out_size, void* d_ws, size_t ws_size,
                              hipStream_t stream)
{
    const float* X  = (const float*)d_in[0];
    const float* Wq = (const float*)d_in[1];
    const float* Wk = (const float*)d_in[2];
    const float* Wv = (const float*)d_in[3];
    float* O = (float*)d_out;

    char* ws = (char*)d_ws;
    size_t off = 0;
    bf16_t* wT = (bf16_t*)(ws + off); off += 192 * 1024 * sizeof(bf16_t);
    bf16_t* qh = (bf16_t*)(ws + off); off += 8192L * 64 * sizeof(bf16_t);
    bf16_t* kh = (bf16_t*)(ws + off); off += 8192L * 64 * sizeof(bf16_t);
    bf16_t* vt = (bf16_t*)(ws + off); off += 64L * 8192 * sizeof(bf16_t);
    f16_t*  pO = (f16_t*)(ws + off);  off += 2L * 64 * SEGS * 64 * 64 * sizeof(f16_t);
    float*  pm = (float*)(ws + off);  off += 2L * 64 * SEGS * 64 * sizeof(float);
    float*  pl = (float*)(ws + off);  off += 2L * 64 * SEGS * 64 * sizeof(float);

    wsplit_k <<<48, 256, 0, stream>>>(Wq, Wk, Wv, wT);
    proj_mfma<<<512, 256, 0, stream>>>(X, wT, qh, kh, vt);
    attn_mfma<<<dim3(512, 2), 256, 0, stream>>>(qh, kh, vt, pO, pm, pl);
    merge_k  <<<dim3(64, 2), 256, 0, stream>>>(pO, pm, pl, O);
}